// Round 4
// baseline (369.537 us; speedup 1.0000x reference)
//
#include <hip/hip_runtime.h>

#define DFEAT 128
#define NGRP 8           // replica groups (blockIdx&7, XCD-aligned by round-robin)
#define SWORDS 8         // words per (grp,node) struct: {cnt, s0..s6} = 32B
#define SSLOT 7          // payload slots per struct
#define OVBKT 64         // overflow buckets (node>>11 -> 0..48)
#define OVCAPB 1024      // capacity per overflow bucket (~20 expected)
#define FILL_BLOCKS 2048 // co-resident fill grid (8 blocks/CU x 256 CU)
#define EPT 8            // max edges per fill thread

typedef __attribute__((ext_vector_type(8))) short short8v;   // 8 bf16
typedef __attribute__((ext_vector_type(4))) float f32x4;     // MFMA C/D
typedef __attribute__((ext_vector_type(4))) unsigned short ushort4v;

__device__ __forceinline__ unsigned short f2bf(float f) {
    union { float f; unsigned u; } cv; cv.f = f;
    unsigned u = cv.u + 0x7fffu + ((cv.u >> 16) & 1u);   // RNE
    return (unsigned short)(u >> 16);
}
__device__ __forceinline__ float bf2f(unsigned short h) {
    union { unsigned u; float f; } cv; cv.u = ((unsigned)h) << 16; return cv.f;
}
__device__ __forceinline__ int load_idx(const void* eiv, int is64, size_t i) {
    return is64 ? (int)((const long long*)eiv)[i] : ((const int*)eiv)[i];
}

// ---------------------------------------------------------------------------
// Fused prep: fill (blocks 0..nfill-1) + W->bf16^T (next 128) + x->bf16 (rest).
// Fill v5: ONE random line-op per edge. Each (grp,node) is a 32B struct
// {cnt, s0..s6}; the cnt atomicAdd and the dependent slot store hit the SAME
// 32B sector (after the RMW owns the line the store is free). Rounds 0-3
// showed the fill is capped at ~14 random line-ops/cycle device-wide,
// insensitive to address layout/scope -> halving ops/edge is the lever.
// Overflow (~1000 edges, P=.0011/bin at lambda=2) goes to per-node-range
// buckets so agg's replay scan stays ~1 trip.
// slab (cnt embedded) + ovcnt pre-zeroed by hipMemsetAsync.
// ---------------------------------------------------------------------------
__global__ __launch_bounds__(256) void prep_kernel(
        const float* __restrict__ W1, const float* __restrict__ W2,
        unsigned short* __restrict__ w1bf, unsigned short* __restrict__ w2bf,
        const float* __restrict__ x, unsigned short* __restrict__ xb, int total4,
        const void* __restrict__ eiv,
        int* __restrict__ ovcnt, int2* __restrict__ ov,
        int* __restrict__ slab,
        int E, int N, int nfill) {
    const int b = blockIdx.x;

    if (b < nfill) {
        // ---- fill part (dst-range sweeps, grp = b&7 replica spread) ----
        const int* e32 = (const int*)eiv;
        int orsum = 0;
#pragma unroll
        for (int i = 0; i < 128; ++i) orsum |= e32[2 * i + 1];
        const int is64 = (orsum == 0);

        const int gtid = b * 256 + threadIdx.x;
        const int stride = nfill * 256;
        const int grp = b & (NGRP - 1);

        int sr[EPT], ds[EPT];
        int k = 0;
        for (int e = gtid; e < E && k < EPT; e += stride) {
            sr[k] = load_idx(eiv, is64, (size_t)e);
            ds[k] = load_idx(eiv, is64, (size_t)E + e);
            ++k;
        }

        const int sz = (N + NGRP - 1) / NGRP;
        for (int s = 0; s < NGRP; ++s) {
            int lo = s * sz, hi = lo + sz;
#pragma unroll
            for (int i = 0; i < EPT; ++i) {
                if (i < k && ds[i] >= lo && ds[i] < hi) {
                    size_t sbase = ((size_t)grp * N + ds[i]) * SWORDS;
                    int pos = atomicAdd(&slab[sbase], 1);   // word0 = cnt
                    if (pos < SSLOT)
                        slab[sbase + 1 + pos] = sr[i];      // same 32B sector
                    else {
                        int bkt = ds[i] >> 11;
                        int o = atomicAdd(&ovcnt[bkt], 1);
                        if (o < OVCAPB) ov[bkt * OVCAPB + o] = make_int2(ds[i], sr[i]);
                    }
                }
            }
        }
    } else if (b < nfill + 128) {
        // ---- W -> bf16 transposed ----
        int wb = b - nfill;
        const float* W = (wb < 64) ? W1 : W2;
        unsigned short* o = (wb < 64) ? w1bf : w2bf;
        int idx = (wb & 63) * 256 + threadIdx.x;   // idx = k*128+n
        int kk = idx >> 7, n = idx & 127;
        o[n * 128 + kk] = f2bf(W[idx]);
    } else {
        // ---- x -> bf16 ----
        int i = (b - nfill - 128) * 256 + threadIdx.x;
        if (i < total4) {
            float4 v = *(const float4*)&x[(size_t)i * 4];
            ushort4v o;
            o.x = f2bf(v.x); o.y = f2bf(v.y); o.z = f2bf(v.z); o.w = f2bf(v.w);
            *(ushort4v*)&xb[(size_t)i * 4] = o;
        }
    }
}

// ---------------------------------------------------------------------------
// Gather-aggregate v5: 32-lane group per node. Lane l reads int2 of struct
// g=l>>2 at words 2p,2p+1 (p=l&3) -> one 32B-chunked coalesced read of all 8
// structs; cnt (word0) broadcast via shfl within the 4-lane subgroup; then
// the round-0-proven ballot/popc compaction (max 8*7=56 entries) and 16-wide
// batched row gathers. Overflow replay scans only this node's bucket.
// ---------------------------------------------------------------------------
__global__ __launch_bounds__(256) void agg_slab_kernel(
        const unsigned short* __restrict__ xb,
        const int* __restrict__ slab,         // [NGRP][N][SWORDS]
        const int* __restrict__ ovcnt, const int2* __restrict__ ov,
        const float* __restrict__ epsp,
        unsigned short* __restrict__ hb,      // bf16 h out (may be null)
        float* __restrict__ hf,               // fp32 h out (used if hb null)
        int N) {
    __shared__ int comp[8][64];
    const int lane = threadIdx.x & 31;
    const int grpq = threadIdx.x >> 5;        // 0..7 node group in block
    const int base = threadIdx.x & 32;        // ballot shift for 32-lane group
    const int node = blockIdx.x * 8 + grpq;
    if (node >= N) return;
    const int c = lane * 4;
    const float epsv = 1.0f + epsp[0];

    // lane l covers struct g=l>>2, words 2p, 2p+1 (p=l&3); word0 is cnt
    int g = lane >> 2, p = lane & 3;
    int2 sl = *(const int2*)&slab[((size_t)g * N + node) * SWORDS + 2 * p];
    int craw = __shfl(sl.x, base + (g << 2), 64);   // struct g word0 = cnt
    int cnt = min(craw, SSLOT);
    int w0 = 2 * p, w1 = 2 * p + 1;                 // word indices
    bool v0 = (w0 >= 1) && (w0 <= cnt);             // word w holds slot w-1
    bool v1 = (w1 <= cnt);
    unsigned m0 = (unsigned)(__ballot(v0) >> base);
    unsigned m1 = (unsigned)(__ballot(v1) >> base);
    int t0 = __popc(m0);
    int total = t0 + __popc(m1);
    unsigned lt = (lane == 0) ? 0u : (~0u >> (32 - lane));
    if (v0) comp[grpq][__popc(m0 & lt)] = sl.x;
    if (v1) comp[grpq][t0 + __popc(m1 & lt)] = sl.y;
    // wave-synchronous LDS: same wave writes then reads its own slice

    ushort4v own = *(const ushort4v*)&xb[(size_t)node * DFEAT + c];
    float ax = epsv * bf2f(own.x), ay = epsv * bf2f(own.y);
    float az = epsv * bf2f(own.z), aw = epsv * bf2f(own.w);

    for (int i = 0; i < total; i += 16) {
        int4 q0 = *(const int4*)&comp[grpq][i];
        int4 q1 = *(const int4*)&comp[grpq][i + 4];
        int4 q2 = *(const int4*)&comp[grpq][i + 8];
        int4 q3 = *(const int4*)&comp[grpq][i + 12];
        int rem = total - i;
        int sj[16];
        sj[0]  = q0.x;
        sj[1]  = (rem > 1)  ? q0.y : q0.x;
        sj[2]  = (rem > 2)  ? q0.z : q0.x;
        sj[3]  = (rem > 3)  ? q0.w : q0.x;
        sj[4]  = (rem > 4)  ? q1.x : q0.x;
        sj[5]  = (rem > 5)  ? q1.y : q0.x;
        sj[6]  = (rem > 6)  ? q1.z : q0.x;
        sj[7]  = (rem > 7)  ? q1.w : q0.x;
        sj[8]  = (rem > 8)  ? q2.x : q0.x;
        sj[9]  = (rem > 9)  ? q2.y : q0.x;
        sj[10] = (rem > 10) ? q2.z : q0.x;
        sj[11] = (rem > 11) ? q2.w : q0.x;
        sj[12] = (rem > 12) ? q3.x : q0.x;
        sj[13] = (rem > 13) ? q3.y : q0.x;
        sj[14] = (rem > 14) ? q3.z : q0.x;
        sj[15] = (rem > 15) ? q3.w : q0.x;
        ushort4v u[16];
#pragma unroll
        for (int q = 0; q < 16; ++q)
            u[q] = *(const ushort4v*)&xb[(size_t)sj[q] * DFEAT + c];
#pragma unroll
        for (int q = 0; q < 16; ++q) {
            if (rem > q) {
                ax += bf2f(u[q].x); ay += bf2f(u[q].y);
                az += bf2f(u[q].z); aw += bf2f(u[q].w);
            }
        }
    }

    // overflow replay: only this node's bucket (~20 entries, L2-resident)
    {
        const int bkt = node >> 11;
        const int2* ovb = &ov[(size_t)bkt * OVCAPB];
        int ovn = min(ovcnt[bkt], OVCAPB);
        int trips = (ovn + 31) >> 5;
        for (int t = 0; t < trips; ++t) {
            int j = t * 32 + lane;
            int2 e = (j < ovn) ? ovb[j] : make_int2(-1, 0);
            unsigned long long bm = __ballot(e.x == node);
            unsigned m = (unsigned)(bm >> base);
            while (m) {
                int l = __ffs(m) - 1; m &= m - 1;
                int s = __shfl(e.y, base + l, 64);
                ushort4v u = *(const ushort4v*)&xb[(size_t)s * DFEAT + c];
                ax += bf2f(u.x); ay += bf2f(u.y);
                az += bf2f(u.z); aw += bf2f(u.w);
            }
        }
    }

    if (hb) {
        ushort4v hv;
        hv.x = f2bf(ax); hv.y = f2bf(ay); hv.z = f2bf(az); hv.w = f2bf(aw);
        *(ushort4v*)&hb[(size_t)node * DFEAT + c] = hv;
    } else {
        *(float4*)&hf[(size_t)node * DFEAT + c] = make_float4(ax, ay, az, aw);
    }
}

// ---------------------------------------------------------------------------
// MFMA MLP (R4-proven): out = relu(h@W1+b1)@W2+b2, bf16 in / fp32 accum.
// ---------------------------------------------------------------------------
__global__ __launch_bounds__(256) void mlp_mfma_kernel(
        const unsigned short* __restrict__ hb,
        const float* __restrict__ hsrc,
        const unsigned short* __restrict__ w1bf,
        const unsigned short* __restrict__ w2bf,
        const float* __restrict__ b1, const float* __restrict__ b2,
        float* __restrict__ out, int N) {
    __shared__ unsigned short hlds[64 * 136];
    __shared__ unsigned short wlds[128 * 136];

    const int tid  = threadIdx.x;
    const int node0 = blockIdx.x * 64;
    const int lane = tid & 63;
    const int w    = tid >> 6;
    const int l15  = lane & 15;
    const int quad = lane >> 4;

    if (hb) {
        for (int i = tid; i < 64 * 16; i += 256) {
            int m = i >> 4, k0 = (i & 15) * 8;
            int node = node0 + m;
            short8v v = {0, 0, 0, 0, 0, 0, 0, 0};
            if (node < N) v = *(const short8v*)&hb[(size_t)node * DFEAT + k0];
            *(short8v*)&hlds[m * 136 + k0] = v;
        }
    } else {
        for (int i = tid; i < 64 * 32; i += 256) {
            int m = i >> 5, c = (i & 31) * 4;
            int node = node0 + m;
            float4 v = make_float4(0.f, 0.f, 0.f, 0.f);
            if (node < N) v = *(const float4*)&hsrc[(size_t)node * DFEAT + c];
            ushort4v o;
            o.x = f2bf(v.x); o.y = f2bf(v.y); o.z = f2bf(v.z); o.w = f2bf(v.w);
            *(ushort4v*)&hlds[m * 136 + c] = o;
        }
    }
    for (int i = tid; i < 128 * 16; i += 256) {
        int n = i >> 4, k0 = (i & 15) * 8;
        *(short8v*)&wlds[n * 136 + k0] = *(const short8v*)&w1bf[n * 128 + k0];
    }
    __syncthreads();

    const unsigned short* ha = &hlds[(w * 16 + l15) * 136 + quad * 8];

    for (int layer = 0; layer < 2; ++layer) {
        if (layer == 1) {
            __syncthreads();
            for (int i = tid; i < 128 * 16; i += 256) {
                int n = i >> 4, k0 = (i & 15) * 8;
                *(short8v*)&wlds[n * 136 + k0] = *(const short8v*)&w2bf[n * 128 + k0];
            }
            __syncthreads();
        }

        f32x4 acc[8];
#pragma unroll
        for (int nt = 0; nt < 8; ++nt) acc[nt] = (f32x4){0.f, 0.f, 0.f, 0.f};

#pragma unroll
        for (int s = 0; s < 4; ++s) {
            short8v a = *(const short8v*)&ha[s * 32];
#pragma unroll
            for (int nt = 0; nt < 8; ++nt) {
                short8v bf = *(const short8v*)&wlds[(nt * 16 + l15) * 136 + quad * 8 + s * 32];
                acc[nt] = __builtin_amdgcn_mfma_f32_16x16x32_bf16(a, bf, acc[nt], 0, 0, 0);
            }
        }

        const float* bias = layer ? b2 : b1;
        if (layer == 0) {
            __syncthreads();
#pragma unroll
            for (int nt = 0; nt < 8; ++nt) {
                float bv = bias[nt * 16 + l15];
#pragma unroll
                for (int r = 0; r < 4; ++r) {
                    float v = fmaxf(acc[nt][r] + bv, 0.f);
                    hlds[(w * 16 + quad * 4 + r) * 136 + nt * 16 + l15] = f2bf(v);
                }
            }
        } else {
#pragma unroll
            for (int nt = 0; nt < 8; ++nt) {
                float bv = bias[nt * 16 + l15];
#pragma unroll
                for (int r = 0; r < 4; ++r) {
                    int node = node0 + w * 16 + quad * 4 + r;
                    if (node < N)
                        out[(size_t)node * DFEAT + nt * 16 + l15] = acc[nt][r] + bv;
                }
            }
        }
    }
}

// ===========================================================================
// Fallback (tiny ws): atomic scatter + fp32 vector MLP
// ===========================================================================
__global__ void detect_idx_kernel(const int* __restrict__ ei, int* __restrict__ flag) {
    if (threadIdx.x == 0 && blockIdx.x == 0) {
        int orsum = 0;
#pragma unroll
        for (int i = 0; i < 128; ++i) orsum |= ei[2 * i + 1];
        flag[0] = (orsum == 0) ? 1 : 0;
    }
}

__global__ __launch_bounds__(256) void scatter_kernel(
        const float* __restrict__ x, const void* __restrict__ eiv,
        const int* __restrict__ flag, float* __restrict__ agg, int E) {
    unsigned gid = blockIdx.x * 256u + threadIdx.x;
    unsigned e = gid >> 5;
    if (e >= (unsigned)E) return;
    int c = (gid & 31u) * 4;
    int is64 = flag[0];
    int src = load_idx(eiv, is64, (size_t)e);
    int dst = load_idx(eiv, is64, (size_t)E + e);
    float4 v = *(const float4*)&x[(size_t)src * DFEAT + c];
    float* p = &agg[(size_t)dst * DFEAT + c];
    unsafeAtomicAdd(p + 0, v.x);
    unsafeAtomicAdd(p + 1, v.y);
    unsafeAtomicAdd(p + 2, v.z);
    unsafeAtomicAdd(p + 3, v.w);
}

__global__ __launch_bounds__(256) void mlp_kernel(
        const float* __restrict__ xp,
        const float* __restrict__ W1, const float* __restrict__ b1,
        const float* __restrict__ W2, const float* __restrict__ b2,
        const float* __restrict__ epsp, float* __restrict__ out) {
    __shared__ float hs[32][DFEAT];
    __shared__ float Wc[64][DFEAT];

    const int tid = threadIdx.x;
    const int node0 = blockIdx.x * 32;
    const float epsv = 1.0f + epsp[0];

    for (int i = tid; i < 32 * (DFEAT / 4); i += 256) {
        int n = i >> 5;
        int c = (i & 31) * 4;
        size_t off = (size_t)(node0 + n) * DFEAT + c;
        float4 h = *(const float4*)&out[off];
        float4 xv = *(const float4*)&xp[off];
        h.x += epsv * xv.x; h.y += epsv * xv.y;
        h.z += epsv * xv.z; h.w += epsv * xv.w;
        *(float4*)&hs[n][c] = h;
    }

    const int og = (tid & 31) * 4;
    const int ng = (tid >> 5) * 4;

    for (int layer = 0; layer < 2; ++layer) {
        const float* W = layer ? W2 : W1;
        const float* b = layer ? b2 : b1;

        float acc[4][4];
#pragma unroll
        for (int j = 0; j < 4; ++j) {
            float bj = b[og + j];
#pragma unroll
            for (int i = 0; i < 4; ++i) acc[i][j] = bj;
        }

        for (int chunk = 0; chunk < 2; ++chunk) {
            __syncthreads();
            for (int i = tid; i < 64 * (DFEAT / 4); i += 256) {
                int r = i >> 5;
                int c = (i & 31) * 4;
                *(float4*)&Wc[r][c] =
                    *(const float4*)&W[(size_t)(chunk * 64 + r) * DFEAT + c];
            }
            __syncthreads();
            const int kb = chunk * 64;
            for (int k = 0; k < 64; k += 4) {
                float4 h4[4], w4[4];
#pragma unroll
                for (int i = 0; i < 4; ++i)
                    h4[i] = *(const float4*)&hs[ng + i][kb + k];
#pragma unroll
                for (int j = 0; j < 4; ++j)
                    w4[j] = *(const float4*)&Wc[k + j][og];
#pragma unroll
                for (int i = 0; i < 4; ++i) {
                    acc[i][0] += h4[i].x * w4[0].x + h4[i].y * w4[1].x
                               + h4[i].z * w4[2].x + h4[i].w * w4[3].x;
                    acc[i][1] += h4[i].x * w4[0].y + h4[i].y * w4[1].y
                               + h4[i].z * w4[2].y + h4[i].w * w4[3].y;
                    acc[i][2] += h4[i].x * w4[0].z + h4[i].y * w4[1].z
                               + h4[i].z * w4[2].z + h4[i].w * w4[3].z;
                    acc[i][3] += h4[i].x * w4[0].w + h4[i].y * w4[1].w
                               + h4[i].z * w4[2].w + h4[i].w * w4[3].w;
                }
            }
        }
        __syncthreads();

        if (layer == 0) {
#pragma unroll
            for (int i = 0; i < 4; ++i) {
                float4 r;
                r.x = fmaxf(acc[i][0], 0.0f);
                r.y = fmaxf(acc[i][1], 0.0f);
                r.z = fmaxf(acc[i][2], 0.0f);
                r.w = fmaxf(acc[i][3], 0.0f);
                *(float4*)&hs[ng + i][og] = r;
            }
        } else {
#pragma unroll
            for (int i = 0; i < 4; ++i) {
                float4 r;
                r.x = acc[i][0]; r.y = acc[i][1];
                r.z = acc[i][2]; r.w = acc[i][3];
                *(float4*)&out[(size_t)(node0 + ng + i) * DFEAT + og] = r;
            }
        }
    }
}

extern "C" void kernel_launch(void* const* d_in, const int* in_sizes, int n_in,
                              void* d_out, int out_size, void* d_ws, size_t ws_size,
                              hipStream_t stream) {
    const float* x   = (const float*)d_in[0];
    const void*  ei  = d_in[1];
    const float* W1  = (const float*)d_in[2];
    const float* b1  = (const float*)d_in[3];
    const float* W2  = (const float*)d_in[4];
    const float* b2  = (const float*)d_in[5];
    const float* eps = (const float*)d_in[6];
    float* out = (float*)d_out;

    const int N = in_sizes[0] / DFEAT;      // 100000
    const int E = in_sizes[1] / 2;          // 1600000
    const int M = NGRP * N;                 // 800000 structs
    const int total4 = N * (DFEAT / 4);     // 3.2M float4s in x

    // ---- layout: [w1bf][w2bf][xb][ov][ovcnt][slab][hb?] ----
    // (ovcnt adjacent to slab so ONE memset zeroes ovcnt + embedded cnts)
    char* p = (char*)d_ws;
    unsigned short* w1bf = (unsigned short*)p;  p += 128 * 128 * 2;
    unsigned short* w2bf = (unsigned short*)p;  p += 128 * 128 * 2;
    unsigned short* xb = (unsigned short*)p;    p += (size_t)N * DFEAT * 2;
    int2* ov = (int2*)p;                        p += (size_t)OVBKT * OVCAPB * 8; // 512KB
    int* ovcnt = (int*)p;                       p += 1024;
    int* slab = (int*)p;                        p += (size_t)M * SWORDS * 4;     // 25.6MB
    size_t need_slim = (size_t)(p - (char*)d_ws);
    unsigned short* hb = (unsigned short*)p;    p += (size_t)N * DFEAT * 2;
    size_t need_full = (size_t)(p - (char*)d_ws);

    if (ws_size >= need_slim) {
        bool full = (ws_size >= need_full);
        int nfill = FILL_BLOCKS;
        if ((size_t)E > (size_t)FILL_BLOCKS * 256 * EPT)
            nfill = (E + 256 * EPT - 1) / (256 * EPT);
        int xbBlocks = (total4 + 255) / 256;

        // one memset: ovcnt (1KB) + slab (cnt words embedded)
        hipMemsetAsync(ovcnt, 0, 1024 + (size_t)M * SWORDS * 4, stream);
        prep_kernel<<<nfill + 128 + xbBlocks, 256, 0, stream>>>(
            W1, W2, w1bf, w2bf, x, xb, total4, ei,
            ovcnt, ov, slab, E, N, nfill);
        agg_slab_kernel<<<(N + 7) / 8, 256, 0, stream>>>(
            xb, slab, ovcnt, ov, eps,
            full ? hb : nullptr, out, N);
        mlp_mfma_kernel<<<(N + 63) / 64, 256, 0, stream>>>(
            full ? hb : nullptr, out, w1bf, w2bf, b1, b2, out, N);
        return;
    }

    // ---- fallback: atomic scatter + fp32 MLP ----
    int* flag3 = (int*)d_ws;
    detect_idx_kernel<<<1, 64, 0, stream>>>((const int*)ei, flag3);
    hipMemsetAsync(d_out, 0, (size_t)out_size * sizeof(float), stream);
    unsigned total = (unsigned)E * 32u;
    scatter_kernel<<<(total + 255u) / 256u, 256, 0, stream>>>(x, ei, flag3, out, E);
    mlp_kernel<<<N / 32, 256, 0, stream>>>(x, W1, b1, W2, b2, eps, out);
}

// Round 5
// 341.613 us; speedup vs baseline: 1.0817x; 1.0817x over previous
//
#include <hip/hip_runtime.h>

#define DFEAT 128
#define NGRP 8           // replica groups (blockIdx&7 ~ XCD round-robin, R0-proven)
#define COMPC 96         // per-node candidate capacity (P(deg>96)~0 for Poisson 16)
#define FILL_BLOCKS 2048 // co-resident fill grid (8 blocks/CU x 256 CU)
#define EPT 8            // max edges per fill thread

typedef __attribute__((ext_vector_type(8))) short short8v;   // 8 bf16
typedef __attribute__((ext_vector_type(4))) float f32x4;     // MFMA C/D
typedef __attribute__((ext_vector_type(4))) unsigned short ushort4v;

__device__ __forceinline__ unsigned short f2bf(float f) {
    union { float f; unsigned u; } cv; cv.f = f;
    unsigned u = cv.u + 0x7fffu + ((cv.u >> 16) & 1u);   // RNE
    return (unsigned short)(u >> 16);
}
__device__ __forceinline__ float bf2f(unsigned short h) {
    union { unsigned u; float f; } cv; cv.u = ((unsigned)h) << 16; return cv.f;
}
__device__ __forceinline__ int load_idx(const void* eiv, int is64, size_t i) {
    return is64 ? (int)((const long long*)eiv)[i] : ((const int*)eiv)[i];
}

// ---------------------------------------------------------------------------
// Fused prep: fill (blocks 0..nfill-1) + W->bf16^T (next 128) + x->bf16 (rest).
// Fill v6 -- linked-list binning, ONE random op per edge:
//   old = atomicExch(&head[grp][node], e)   <- random returning-atomic, same
//        grp-pure line discipline as R0's proven counts (95us profile)
//   nxt2[e] = {src, old}                    <- COALESCED (e consecutive across
//        lanes per unroll step), separate streaming region, never shares a
//        line with atomics (R4's same-line poison structurally excluded)
// Random-op budget/edge: 2 -> 1. Slab + overflow machinery deleted.
// head pre-set to -1 by hipMemsetAsync(0xFF). Sweeps kept (R8-proven window).
// ---------------------------------------------------------------------------
__global__ __launch_bounds__(256) void prep_kernel(
        const float* __restrict__ W1, const float* __restrict__ W2,
        unsigned short* __restrict__ w1bf, unsigned short* __restrict__ w2bf,
        const float* __restrict__ x, unsigned short* __restrict__ xb, int total4,
        const void* __restrict__ eiv,
        int* __restrict__ head, int2* __restrict__ nxt2,
        int E, int N, int nfill) {
    const int b = blockIdx.x;

    if (b < nfill) {
        // ---- fill part (dst-range sweeps, grp = b&7 replica spread) ----
        const int* e32 = (const int*)eiv;
        int orsum = 0;
#pragma unroll
        for (int i = 0; i < 128; ++i) orsum |= e32[2 * i + 1];
        const int is64 = (orsum == 0);

        const int gtid = b * 256 + threadIdx.x;
        const int stride = nfill * 256;
        const int grp = b & (NGRP - 1);

        int sr[EPT], ds[EPT];
        int k = 0;
        for (int e = gtid; e < E && k < EPT; e += stride) {
            sr[k] = load_idx(eiv, is64, (size_t)e);
            ds[k] = load_idx(eiv, is64, (size_t)E + e);
            ++k;
        }

        const int sz = (N + NGRP - 1) / NGRP;
        for (int s = 0; s < NGRP; ++s) {
            int lo = s * sz, hi = lo + sz;
#pragma unroll
            for (int i = 0; i < EPT; ++i) {
                if (i < k && ds[i] >= lo && ds[i] < hi) {
                    int e = gtid + i * stride;                 // edge id
                    int old = atomicExch(&head[(size_t)grp * N + ds[i]], e);
                    nxt2[e] = make_int2(sr[i], old);           // coalesced 8B
                }
            }
        }
    } else if (b < nfill + 128) {
        // ---- W -> bf16 transposed ----
        int wb = b - nfill;
        const float* W = (wb < 64) ? W1 : W2;
        unsigned short* o = (wb < 64) ? w1bf : w2bf;
        int idx = (wb & 63) * 256 + threadIdx.x;   // idx = k*128+n
        int kk = idx >> 7, n = idx & 127;
        o[n * 128 + kk] = f2bf(W[idx]);
    } else {
        // ---- x -> bf16 ----
        int i = (b - nfill - 128) * 256 + threadIdx.x;
        if (i < total4) {
            float4 v = *(const float4*)&x[(size_t)i * 4];
            ushort4v o;
            o.x = f2bf(v.x); o.y = f2bf(v.y); o.z = f2bf(v.z); o.w = f2bf(v.w);
            *(ushort4v*)&xb[(size_t)i * 4] = o;
        }
    }
}

// ---------------------------------------------------------------------------
// Gather-aggregate v6: 32-lane group per node. Lanes 0..7 walk the 8 grp
// chains in parallel (expected max depth ~4-5, 8B L2/L3 loads, hidden by
// occupancy); srcs appended to LDS comp via the R0-proven ballot/popc idiom
// (wave-synchronous, no barrier); then the unchanged 16-wide batched row
// gathers. h = (1+eps)*x[n] + sum x[s]. No overflow path (lists are exact).
// ---------------------------------------------------------------------------
__global__ __launch_bounds__(256) void agg_slab_kernel(
        const unsigned short* __restrict__ xb,
        const int* __restrict__ head,         // [NGRP][N]
        const int2* __restrict__ nxt2,        // [E] {src, next}
        const float* __restrict__ epsp,
        unsigned short* __restrict__ hb,      // bf16 h out (may be null)
        float* __restrict__ hf,               // fp32 h out (used if hb null)
        int N) {
    __shared__ int comp[8][COMPC];
    const int lane = threadIdx.x & 31;
    const int grpq = threadIdx.x >> 5;        // 0..7 node group in block
    const int base = threadIdx.x & 32;        // ballot shift for 32-lane group
    const int node = blockIdx.x * 8 + grpq;
    if (node >= N) return;
    const int c = lane * 4;
    const float epsv = 1.0f + epsp[0];

    // ---- chain walk: lanes 0..7 own grp=lane ----
    int p = -1;
    if (lane < NGRP) p = head[(size_t)lane * N + node];
    int total = 0;
    const unsigned lt = (lane == 0) ? 0u : (~0u >> (32 - lane));
    for (;;) {
        bool act = (p >= 0);
        unsigned m = (unsigned)(__ballot(act) >> base);
        if (!m) break;
        int2 v = make_int2(0, -1);
        if (act) v = nxt2[p];
        if (act) {
            int idx = total + __popc(m & lt);
            if (idx < COMPC) comp[grpq][idx] = v.x;
        }
        total += __popc(m);
        p = act ? v.y : -1;
    }
    if (total > COMPC) total = COMPC;
    // wave-synchronous LDS: same wave writes then reads its own slice

    ushort4v own = *(const ushort4v*)&xb[(size_t)node * DFEAT + c];
    float ax = epsv * bf2f(own.x), ay = epsv * bf2f(own.y);
    float az = epsv * bf2f(own.z), aw = epsv * bf2f(own.w);

    for (int i = 0; i < total; i += 16) {
        int4 q0 = *(const int4*)&comp[grpq][i];
        int4 q1 = *(const int4*)&comp[grpq][i + 4];
        int4 q2 = *(const int4*)&comp[grpq][i + 8];
        int4 q3 = *(const int4*)&comp[grpq][i + 12];
        int rem = total - i;
        int sj[16];
        sj[0]  = q0.x;
        sj[1]  = (rem > 1)  ? q0.y : q0.x;
        sj[2]  = (rem > 2)  ? q0.z : q0.x;
        sj[3]  = (rem > 3)  ? q0.w : q0.x;
        sj[4]  = (rem > 4)  ? q1.x : q0.x;
        sj[5]  = (rem > 5)  ? q1.y : q0.x;
        sj[6]  = (rem > 6)  ? q1.z : q0.x;
        sj[7]  = (rem > 7)  ? q1.w : q0.x;
        sj[8]  = (rem > 8)  ? q2.x : q0.x;
        sj[9]  = (rem > 9)  ? q2.y : q0.x;
        sj[10] = (rem > 10) ? q2.z : q0.x;
        sj[11] = (rem > 11) ? q2.w : q0.x;
        sj[12] = (rem > 12) ? q3.x : q0.x;
        sj[13] = (rem > 13) ? q3.y : q0.x;
        sj[14] = (rem > 14) ? q3.z : q0.x;
        sj[15] = (rem > 15) ? q3.w : q0.x;
        ushort4v u[16];
#pragma unroll
        for (int q = 0; q < 16; ++q)
            u[q] = *(const ushort4v*)&xb[(size_t)sj[q] * DFEAT + c];
#pragma unroll
        for (int q = 0; q < 16; ++q) {
            if (rem > q) {
                ax += bf2f(u[q].x); ay += bf2f(u[q].y);
                az += bf2f(u[q].z); aw += bf2f(u[q].w);
            }
        }
    }

    if (hb) {
        ushort4v hv;
        hv.x = f2bf(ax); hv.y = f2bf(ay); hv.z = f2bf(az); hv.w = f2bf(aw);
        *(ushort4v*)&hb[(size_t)node * DFEAT + c] = hv;
    } else {
        *(float4*)&hf[(size_t)node * DFEAT + c] = make_float4(ax, ay, az, aw);
    }
}

// ---------------------------------------------------------------------------
// MFMA MLP (R4-proven): out = relu(h@W1+b1)@W2+b2, bf16 in / fp32 accum.
// ---------------------------------------------------------------------------
__global__ __launch_bounds__(256) void mlp_mfma_kernel(
        const unsigned short* __restrict__ hb,
        const float* __restrict__ hsrc,
        const unsigned short* __restrict__ w1bf,
        const unsigned short* __restrict__ w2bf,
        const float* __restrict__ b1, const float* __restrict__ b2,
        float* __restrict__ out, int N) {
    __shared__ unsigned short hlds[64 * 136];
    __shared__ unsigned short wlds[128 * 136];

    const int tid  = threadIdx.x;
    const int node0 = blockIdx.x * 64;
    const int lane = tid & 63;
    const int w    = tid >> 6;
    const int l15  = lane & 15;
    const int quad = lane >> 4;

    if (hb) {
        for (int i = tid; i < 64 * 16; i += 256) {
            int m = i >> 4, k0 = (i & 15) * 8;
            int node = node0 + m;
            short8v v = {0, 0, 0, 0, 0, 0, 0, 0};
            if (node < N) v = *(const short8v*)&hb[(size_t)node * DFEAT + k0];
            *(short8v*)&hlds[m * 136 + k0] = v;
        }
    } else {
        for (int i = tid; i < 64 * 32; i += 256) {
            int m = i >> 5, c = (i & 31) * 4;
            int node = node0 + m;
            float4 v = make_float4(0.f, 0.f, 0.f, 0.f);
            if (node < N) v = *(const float4*)&hsrc[(size_t)node * DFEAT + c];
            ushort4v o;
            o.x = f2bf(v.x); o.y = f2bf(v.y); o.z = f2bf(v.z); o.w = f2bf(v.w);
            *(ushort4v*)&hlds[m * 136 + c] = o;
        }
    }
    for (int i = tid; i < 128 * 16; i += 256) {
        int n = i >> 4, k0 = (i & 15) * 8;
        *(short8v*)&wlds[n * 136 + k0] = *(const short8v*)&w1bf[n * 128 + k0];
    }
    __syncthreads();

    const unsigned short* ha = &hlds[(w * 16 + l15) * 136 + quad * 8];

    for (int layer = 0; layer < 2; ++layer) {
        if (layer == 1) {
            __syncthreads();
            for (int i = tid; i < 128 * 16; i += 256) {
                int n = i >> 4, k0 = (i & 15) * 8;
                *(short8v*)&wlds[n * 136 + k0] = *(const short8v*)&w2bf[n * 128 + k0];
            }
            __syncthreads();
        }

        f32x4 acc[8];
#pragma unroll
        for (int nt = 0; nt < 8; ++nt) acc[nt] = (f32x4){0.f, 0.f, 0.f, 0.f};

#pragma unroll
        for (int s = 0; s < 4; ++s) {
            short8v a = *(const short8v*)&ha[s * 32];
#pragma unroll
            for (int nt = 0; nt < 8; ++nt) {
                short8v bf = *(const short8v*)&wlds[(nt * 16 + l15) * 136 + quad * 8 + s * 32];
                acc[nt] = __builtin_amdgcn_mfma_f32_16x16x32_bf16(a, bf, acc[nt], 0, 0, 0);
            }
        }

        const float* bias = layer ? b2 : b1;
        if (layer == 0) {
            __syncthreads();
#pragma unroll
            for (int nt = 0; nt < 8; ++nt) {
                float bv = bias[nt * 16 + l15];
#pragma unroll
                for (int r = 0; r < 4; ++r) {
                    float v = fmaxf(acc[nt][r] + bv, 0.f);
                    hlds[(w * 16 + quad * 4 + r) * 136 + nt * 16 + l15] = f2bf(v);
                }
            }
        } else {
#pragma unroll
            for (int nt = 0; nt < 8; ++nt) {
                float bv = bias[nt * 16 + l15];
#pragma unroll
                for (int r = 0; r < 4; ++r) {
                    int node = node0 + w * 16 + quad * 4 + r;
                    if (node < N)
                        out[(size_t)node * DFEAT + nt * 16 + l15] = acc[nt][r] + bv;
                }
            }
        }
    }
}

// ===========================================================================
// Fallback (tiny ws): atomic scatter + fp32 vector MLP
// ===========================================================================
__global__ void detect_idx_kernel(const int* __restrict__ ei, int* __restrict__ flag) {
    if (threadIdx.x == 0 && blockIdx.x == 0) {
        int orsum = 0;
#pragma unroll
        for (int i = 0; i < 128; ++i) orsum |= ei[2 * i + 1];
        flag[0] = (orsum == 0) ? 1 : 0;
    }
}

__global__ __launch_bounds__(256) void scatter_kernel(
        const float* __restrict__ x, const void* __restrict__ eiv,
        const int* __restrict__ flag, float* __restrict__ agg, int E) {
    unsigned gid = blockIdx.x * 256u + threadIdx.x;
    unsigned e = gid >> 5;
    if (e >= (unsigned)E) return;
    int c = (gid & 31u) * 4;
    int is64 = flag[0];
    int src = load_idx(eiv, is64, (size_t)e);
    int dst = load_idx(eiv, is64, (size_t)E + e);
    float4 v = *(const float4*)&x[(size_t)src * DFEAT + c];
    float* p = &agg[(size_t)dst * DFEAT + c];
    unsafeAtomicAdd(p + 0, v.x);
    unsafeAtomicAdd(p + 1, v.y);
    unsafeAtomicAdd(p + 2, v.z);
    unsafeAtomicAdd(p + 3, v.w);
}

__global__ __launch_bounds__(256) void mlp_kernel(
        const float* __restrict__ xp,
        const float* __restrict__ W1, const float* __restrict__ b1,
        const float* __restrict__ W2, const float* __restrict__ b2,
        const float* __restrict__ epsp, float* __restrict__ out) {
    __shared__ float hs[32][DFEAT];
    __shared__ float Wc[64][DFEAT];

    const int tid = threadIdx.x;
    const int node0 = blockIdx.x * 32;
    const float epsv = 1.0f + epsp[0];

    for (int i = tid; i < 32 * (DFEAT / 4); i += 256) {
        int n = i >> 5;
        int c = (i & 31) * 4;
        size_t off = (size_t)(node0 + n) * DFEAT + c;
        float4 h = *(const float4*)&out[off];
        float4 xv = *(const float4*)&xp[off];
        h.x += epsv * xv.x; h.y += epsv * xv.y;
        h.z += epsv * xv.z; h.w += epsv * xv.w;
        *(float4*)&hs[n][c] = h;
    }

    const int og = (tid & 31) * 4;
    const int ng = (tid >> 5) * 4;

    for (int layer = 0; layer < 2; ++layer) {
        const float* W = layer ? W2 : W1;
        const float* b = layer ? b2 : b1;

        float acc[4][4];
#pragma unroll
        for (int j = 0; j < 4; ++j) {
            float bj = b[og + j];
#pragma unroll
            for (int i = 0; i < 4; ++i) acc[i][j] = bj;
        }

        for (int chunk = 0; chunk < 2; ++chunk) {
            __syncthreads();
            for (int i = tid; i < 64 * (DFEAT / 4); i += 256) {
                int r = i >> 5;
                int c = (i & 31) * 4;
                *(float4*)&Wc[r][c] =
                    *(const float4*)&W[(size_t)(chunk * 64 + r) * DFEAT + c];
            }
            __syncthreads();
            const int kb = chunk * 64;
            for (int k = 0; k < 64; k += 4) {
                float4 h4[4], w4[4];
#pragma unroll
                for (int i = 0; i < 4; ++i)
                    h4[i] = *(const float4*)&hs[ng + i][kb + k];
#pragma unroll
                for (int j = 0; j < 4; ++j)
                    w4[j] = *(const float4*)&Wc[k + j][og];
#pragma unroll
                for (int i = 0; i < 4; ++i) {
                    acc[i][0] += h4[i].x * w4[0].x + h4[i].y * w4[1].x
                               + h4[i].z * w4[2].x + h4[i].w * w4[3].x;
                    acc[i][1] += h4[i].x * w4[0].y + h4[i].y * w4[1].y
                               + h4[i].z * w4[2].y + h4[i].w * w4[3].y;
                    acc[i][2] += h4[i].x * w4[0].z + h4[i].y * w4[1].z
                               + h4[i].z * w4[2].z + h4[i].w * w4[3].z;
                    acc[i][3] += h4[i].x * w4[0].w + h4[i].y * w4[1].w
                               + h4[i].z * w4[2].w + h4[i].w * w4[3].w;
                }
            }
        }
        __syncthreads();

        if (layer == 0) {
#pragma unroll
            for (int i = 0; i < 4; ++i) {
                float4 r;
                r.x = fmaxf(acc[i][0], 0.0f);
                r.y = fmaxf(acc[i][1], 0.0f);
                r.z = fmaxf(acc[i][2], 0.0f);
                r.w = fmaxf(acc[i][3], 0.0f);
                *(float4*)&hs[ng + i][og] = r;
            }
        } else {
#pragma unroll
            for (int i = 0; i < 4; ++i) {
                float4 r;
                r.x = acc[i][0]; r.y = acc[i][1];
                r.z = acc[i][2]; r.w = acc[i][3];
                *(float4*)&out[(size_t)(node0 + ng + i) * DFEAT + og] = r;
            }
        }
    }
}

extern "C" void kernel_launch(void* const* d_in, const int* in_sizes, int n_in,
                              void* d_out, int out_size, void* d_ws, size_t ws_size,
                              hipStream_t stream) {
    const float* x   = (const float*)d_in[0];
    const void*  ei  = d_in[1];
    const float* W1  = (const float*)d_in[2];
    const float* b1  = (const float*)d_in[3];
    const float* W2  = (const float*)d_in[4];
    const float* b2  = (const float*)d_in[5];
    const float* eps = (const float*)d_in[6];
    float* out = (float*)d_out;

    const int N = in_sizes[0] / DFEAT;      // 100000
    const int E = in_sizes[1] / 2;          // 1600000
    const int M = NGRP * N;                 // 800000 list heads
    const int total4 = N * (DFEAT / 4);     // 3.2M float4s in x

    // ---- layout: [w1bf][w2bf][xb][head][nxt2][hb?] ----
    char* p = (char*)d_ws;
    unsigned short* w1bf = (unsigned short*)p;  p += 128 * 128 * 2;
    unsigned short* w2bf = (unsigned short*)p;  p += 128 * 128 * 2;
    unsigned short* xb = (unsigned short*)p;    p += (size_t)N * DFEAT * 2;
    int* head = (int*)p;                        p += (size_t)M * 4;       // 3.2MB
    int2* nxt2 = (int2*)p;                      p += (size_t)E * 8;      // 12.8MB
    size_t need_slim = (size_t)(p - (char*)d_ws);
    unsigned short* hb = (unsigned short*)p;    p += (size_t)N * DFEAT * 2;
    size_t need_full = (size_t)(p - (char*)d_ws);

    if (ws_size >= need_slim) {
        bool full = (ws_size >= need_full);
        int nfill = FILL_BLOCKS;
        if ((size_t)E > (size_t)FILL_BLOCKS * 256 * EPT)
            nfill = (E + 256 * EPT - 1) / (256 * EPT);
        int xbBlocks = (total4 + 255) / 256;

        hipMemsetAsync(head, 0xFF, (size_t)M * 4, stream);   // heads = -1
        prep_kernel<<<nfill + 128 + xbBlocks, 256, 0, stream>>>(
            W1, W2, w1bf, w2bf, x, xb, total4, ei,
            head, nxt2, E, N, nfill);
        agg_slab_kernel<<<(N + 7) / 8, 256, 0, stream>>>(
            xb, head, nxt2, eps,
            full ? hb : nullptr, out, N);
        mlp_mfma_kernel<<<(N + 63) / 64, 256, 0, stream>>>(
            full ? hb : nullptr, out, w1bf, w2bf, b1, b2, out, N);
        return;
    }

    // ---- fallback: atomic scatter + fp32 MLP ----
    int* flag3 = (int*)d_ws;
    detect_idx_kernel<<<1, 64, 0, stream>>>((const int*)ei, flag3);
    hipMemsetAsync(d_out, 0, (size_t)out_size * sizeof(float), stream);
    unsigned total = (unsigned)E * 32u;
    scatter_kernel<<<(total + 255u) / 256u, 256, 0, stream>>>(x, ei, flag3, out, E);
    mlp_kernel<<<N / 32, 256, 0, stream>>>(x, W1, b1, W2, b2, eps, out);
}

// Round 6
// 294.968 us; speedup vs baseline: 1.2528x; 1.1581x over previous
//
#include <hip/hip_runtime.h>

#define DFEAT 128
#define NGRP 8           // slab groups (blockIdx&7 ~ XCD round-robin, R0-proven)
#define SSLOT 8          // slab slots per (grp, node) segment
#define OVCAP 32768      // overflow list capacity (expected ~200 used)
#define FILL_BLOCKS 2048 // co-resident fill grid (8 blocks/CU x 256 CU)
#define EPT 8            // max edges per fill thread

typedef __attribute__((ext_vector_type(8))) short short8v;   // 8 bf16
typedef __attribute__((ext_vector_type(4))) float f32x4;     // MFMA C/D
typedef __attribute__((ext_vector_type(4))) unsigned short ushort4v;

__device__ __forceinline__ unsigned short f2bf(float f) {
    union { float f; unsigned u; } cv; cv.f = f;
    unsigned u = cv.u + 0x7fffu + ((cv.u >> 16) & 1u);   // RNE
    return (unsigned short)(u >> 16);
}
__device__ __forceinline__ float bf2f(unsigned short h) {
    union { unsigned u; float f; } cv; cv.u = ((unsigned)h) << 16; return cv.f;
}
__device__ __forceinline__ int load_idx(const void* eiv, int is64, size_t i) {
    return is64 ? (int)((const long long*)eiv)[i] : ((const int*)eiv)[i];
}

// ---------------------------------------------------------------------------
// Fused prep (ROUND-0 VERBATIM, measured 95us): fill (blocks 0..nfill-1,
// launched first: latency-bound, overlaps the BW-bound converts) +
// W->bf16^T (next 128 blocks) + x->bf16 (rest).
// Rounds 1-5 falsified every rearrangement of this fill (unified counts,
// interleaved lines, XCC keying, merged count+slot, linked lists): all were
// 104-172us vs this structure's 95us. Do not touch.
// counts/ovcnt pre-zeroed by hipMemsetAsync.
// ---------------------------------------------------------------------------
__global__ __launch_bounds__(256) void prep_kernel(
        const float* __restrict__ W1, const float* __restrict__ W2,
        unsigned short* __restrict__ w1bf, unsigned short* __restrict__ w2bf,
        const float* __restrict__ x, unsigned short* __restrict__ xb, int total4,
        const void* __restrict__ eiv,
        int* __restrict__ counts, int* __restrict__ ovcnt,
        int2* __restrict__ ov, int* __restrict__ slab,
        int E, int N, int nfill) {
    const int b = blockIdx.x;

    if (b < nfill) {
        // ---- fill part (dst-range sweeps) ----
        const int* e32 = (const int*)eiv;
        int orsum = 0;
#pragma unroll
        for (int i = 0; i < 128; ++i) orsum |= e32[2 * i + 1];
        const int is64 = (orsum == 0);

        const int gtid = b * 256 + threadIdx.x;
        const int stride = nfill * 256;
        const int grp = b & (NGRP - 1);

        int sr[EPT], ds[EPT];
        int k = 0;
        for (int e = gtid; e < E && k < EPT; e += stride) {
            sr[k] = load_idx(eiv, is64, (size_t)e);
            ds[k] = load_idx(eiv, is64, (size_t)E + e);
            ++k;
        }

        const int sz = (N + NGRP - 1) / NGRP;
        for (int s = 0; s < NGRP; ++s) {
            int lo = s * sz, hi = lo + sz;
#pragma unroll
            for (int i = 0; i < EPT; ++i) {
                if (i < k && ds[i] >= lo && ds[i] < hi) {
                    int pos = atomicAdd(&counts[(size_t)grp * N + ds[i]], 1);
                    if (pos < SSLOT)
                        slab[((size_t)grp * N + ds[i]) * SSLOT + pos] = sr[i];
                    else {
                        int o = atomicAdd(ovcnt, 1);
                        if (o < OVCAP) ov[o] = make_int2(ds[i], sr[i]);
                    }
                }
            }
        }
    } else if (b < nfill + 128) {
        // ---- W -> bf16 transposed ----
        int wb = b - nfill;
        const float* W = (wb < 64) ? W1 : W2;
        unsigned short* o = (wb < 64) ? w1bf : w2bf;
        int idx = (wb & 63) * 256 + threadIdx.x;   // idx = k*128+n
        int kk = idx >> 7, n = idx & 127;
        o[n * 128 + kk] = f2bf(W[idx]);
    } else {
        // ---- x -> bf16 ----
        int i = (b - nfill - 128) * 256 + threadIdx.x;
        if (i < total4) {
            float4 v = *(const float4*)&x[(size_t)i * 4];
            ushort4v o;
            o.x = f2bf(v.x); o.y = f2bf(v.y); o.z = f2bf(v.z); o.w = f2bf(v.w);
            *(ushort4v*)&xb[(size_t)i * 4] = o;
        }
    }
}

// ---------------------------------------------------------------------------
// Gather-aggregate v7: segment-major STAGED front end. A block's 8 nodes
// make each grp's slab sub-rows contiguous: slab[g][node0..node0+7][8] is
// one 256B span, counts[g][node0..node0+7] one 32B span. 256 threads stage
// all 8 spans into LDS with fully coalesced reads (8 lines + 8 sectors per
// block vs ~72 random lines in the R0 agg -- R1 measured this coalescing
// worth ~20-25us), one barrier, then the R0-proven ballot/popc compaction
// reads from LDS, and the unchanged 16-wide batched row gathers.
// ---------------------------------------------------------------------------
__global__ __launch_bounds__(256) void agg_slab_kernel(
        const unsigned short* __restrict__ xb,
        const int* __restrict__ counts,       // [NGRP][N]
        const int* __restrict__ slab,         // [NGRP][N][SSLOT]
        const int* __restrict__ ovcnt, const int2* __restrict__ ov,
        const float* __restrict__ epsp,
        unsigned short* __restrict__ hb,      // bf16 h out (may be null)
        float* __restrict__ hf,               // fp32 h out (used if hb null)
        int N) {
    __shared__ int raw[8][66];    // [grp][(node-node0)*8+slot], pad 66: spread banks
    __shared__ int rcnt[8][8];    // [grp][node-node0]
    __shared__ int comp[8][64];
    const int tid  = threadIdx.x;
    const int node0 = blockIdx.x * 8;

    // ---- coalesced stage: 32-lane team g loads grp g's 256B slab span ----
    {
        int g = tid >> 5, l = tid & 31;
        if (node0 + 8 <= N) {
            const int* sp = &slab[((size_t)g * N + node0) * SSLOT];
            int2 v = *(const int2*)&sp[l * 2];
            raw[g][l * 2] = v.x; raw[g][l * 2 + 1] = v.y;
            if (l < 8) rcnt[g][l] = counts[(size_t)g * N + node0 + l];
        } else {
            // tail block: per-element guarded
            int nn = (l * 2) >> 3;   // node-in-block of first word
            if (node0 + nn < N) {
                const int* sp = &slab[((size_t)g * N + node0) * SSLOT];
                raw[g][l * 2] = sp[l * 2];
                raw[g][l * 2 + 1] = sp[l * 2 + 1];
            } else {
                raw[g][l * 2] = 0; raw[g][l * 2 + 1] = 0;
            }
            if (l < 8) rcnt[g][l] = (node0 + l < N)
                ? counts[(size_t)g * N + node0 + l] : 0;
        }
    }
    __syncthreads();

    const int lane = tid & 31;
    const int grpq = tid >> 5;                // node-in-block this team computes
    const int base = tid & 32;                // ballot shift for 32-lane group
    const int node = node0 + grpq;
    if (node >= N) return;                    // after the only barrier: safe
    const int c = lane * 4;
    const float epsv = 1.0f + epsp[0];

    // lane l covers grp g=l>>2, slots (l&3)*2, (l&3)*2+1 -- from LDS now
    int g = lane >> 2, s0 = (lane & 3) * 2;
    int vx = raw[g][grpq * 8 + s0];
    int vy = raw[g][grpq * 8 + s0 + 1];
    int cnt = min(rcnt[g][grpq], SSLOT);
    bool v0 = s0 < cnt, v1 = (s0 + 1) < cnt;
    unsigned m0 = (unsigned)(__ballot(v0) >> base);
    unsigned m1 = (unsigned)(__ballot(v1) >> base);
    int t0 = __popc(m0);
    int total = t0 + __popc(m1);
    unsigned lt = (lane == 0) ? 0u : (~0u >> (32 - lane));
    if (v0) comp[grpq][__popc(m0 & lt)] = vx;
    if (v1) comp[grpq][t0 + __popc(m1 & lt)] = vy;
    // wave-synchronous LDS: same wave writes then reads its own slice

    ushort4v own = *(const ushort4v*)&xb[(size_t)node * DFEAT + c];
    float ax = epsv * bf2f(own.x), ay = epsv * bf2f(own.y);
    float az = epsv * bf2f(own.z), aw = epsv * bf2f(own.w);

    for (int i = 0; i < total; i += 16) {
        int4 q0 = *(const int4*)&comp[grpq][i];
        int4 q1 = *(const int4*)&comp[grpq][i + 4];
        int4 q2 = *(const int4*)&comp[grpq][i + 8];
        int4 q3 = *(const int4*)&comp[grpq][i + 12];
        int rem = total - i;
        int sj[16];
        sj[0]  = q0.x;
        sj[1]  = (rem > 1)  ? q0.y : q0.x;
        sj[2]  = (rem > 2)  ? q0.z : q0.x;
        sj[3]  = (rem > 3)  ? q0.w : q0.x;
        sj[4]  = (rem > 4)  ? q1.x : q0.x;
        sj[5]  = (rem > 5)  ? q1.y : q0.x;
        sj[6]  = (rem > 6)  ? q1.z : q0.x;
        sj[7]  = (rem > 7)  ? q1.w : q0.x;
        sj[8]  = (rem > 8)  ? q2.x : q0.x;
        sj[9]  = (rem > 9)  ? q2.y : q0.x;
        sj[10] = (rem > 10) ? q2.z : q0.x;
        sj[11] = (rem > 11) ? q2.w : q0.x;
        sj[12] = (rem > 12) ? q3.x : q0.x;
        sj[13] = (rem > 13) ? q3.y : q0.x;
        sj[14] = (rem > 14) ? q3.z : q0.x;
        sj[15] = (rem > 15) ? q3.w : q0.x;
        ushort4v u[16];
#pragma unroll
        for (int q = 0; q < 16; ++q)
            u[q] = *(const ushort4v*)&xb[(size_t)sj[q] * DFEAT + c];
#pragma unroll
        for (int q = 0; q < 16; ++q) {
            if (rem > q) {
                ax += bf2f(u[q].x); ay += bf2f(u[q].y);
                az += bf2f(u[q].z); aw += bf2f(u[q].w);
            }
        }
    }

    // overflow replay (tiny list, L2-resident)
    int ovn = min(ovcnt[0], OVCAP);
    int trips = (ovn + 31) >> 5;
    for (int t = 0; t < trips; ++t) {
        int j = t * 32 + lane;
        int2 e = (j < ovn) ? ov[j] : make_int2(-1, 0);
        unsigned long long bm = __ballot(e.x == node);
        unsigned m = (unsigned)(bm >> base);
        while (m) {
            int l = __ffs(m) - 1; m &= m - 1;
            int s = __shfl(e.y, base + l, 64);
            ushort4v u = *(const ushort4v*)&xb[(size_t)s * DFEAT + c];
            ax += bf2f(u.x); ay += bf2f(u.y);
            az += bf2f(u.z); aw += bf2f(u.w);
        }
    }

    if (hb) {
        ushort4v hv;
        hv.x = f2bf(ax); hv.y = f2bf(ay); hv.z = f2bf(az); hv.w = f2bf(aw);
        *(ushort4v*)&hb[(size_t)node * DFEAT + c] = hv;
    } else {
        *(float4*)&hf[(size_t)node * DFEAT + c] = make_float4(ax, ay, az, aw);
    }
}

// ---------------------------------------------------------------------------
// MFMA MLP (R4-proven): out = relu(h@W1+b1)@W2+b2, bf16 in / fp32 accum.
// ---------------------------------------------------------------------------
__global__ __launch_bounds__(256) void mlp_mfma_kernel(
        const unsigned short* __restrict__ hb,
        const float* __restrict__ hsrc,
        const unsigned short* __restrict__ w1bf,
        const unsigned short* __restrict__ w2bf,
        const float* __restrict__ b1, const float* __restrict__ b2,
        float* __restrict__ out, int N) {
    __shared__ unsigned short hlds[64 * 136];
    __shared__ unsigned short wlds[128 * 136];

    const int tid  = threadIdx.x;
    const int node0 = blockIdx.x * 64;
    const int lane = tid & 63;
    const int w    = tid >> 6;
    const int l15  = lane & 15;
    const int quad = lane >> 4;

    if (hb) {
        for (int i = tid; i < 64 * 16; i += 256) {
            int m = i >> 4, k0 = (i & 15) * 8;
            int node = node0 + m;
            short8v v = {0, 0, 0, 0, 0, 0, 0, 0};
            if (node < N) v = *(const short8v*)&hb[(size_t)node * DFEAT + k0];
            *(short8v*)&hlds[m * 136 + k0] = v;
        }
    } else {
        for (int i = tid; i < 64 * 32; i += 256) {
            int m = i >> 5, c = (i & 31) * 4;
            int node = node0 + m;
            float4 v = make_float4(0.f, 0.f, 0.f, 0.f);
            if (node < N) v = *(const float4*)&hsrc[(size_t)node * DFEAT + c];
            ushort4v o;
            o.x = f2bf(v.x); o.y = f2bf(v.y); o.z = f2bf(v.z); o.w = f2bf(v.w);
            *(ushort4v*)&hlds[m * 136 + c] = o;
        }
    }
    for (int i = tid; i < 128 * 16; i += 256) {
        int n = i >> 4, k0 = (i & 15) * 8;
        *(short8v*)&wlds[n * 136 + k0] = *(const short8v*)&w1bf[n * 128 + k0];
    }
    __syncthreads();

    const unsigned short* ha = &hlds[(w * 16 + l15) * 136 + quad * 8];

    for (int layer = 0; layer < 2; ++layer) {
        if (layer == 1) {
            __syncthreads();
            for (int i = tid; i < 128 * 16; i += 256) {
                int n = i >> 4, k0 = (i & 15) * 8;
                *(short8v*)&wlds[n * 136 + k0] = *(const short8v*)&w2bf[n * 128 + k0];
            }
            __syncthreads();
        }

        f32x4 acc[8];
#pragma unroll
        for (int nt = 0; nt < 8; ++nt) acc[nt] = (f32x4){0.f, 0.f, 0.f, 0.f};

#pragma unroll
        for (int s = 0; s < 4; ++s) {
            short8v a = *(const short8v*)&ha[s * 32];
#pragma unroll
            for (int nt = 0; nt < 8; ++nt) {
                short8v bf = *(const short8v*)&wlds[(nt * 16 + l15) * 136 + quad * 8 + s * 32];
                acc[nt] = __builtin_amdgcn_mfma_f32_16x16x32_bf16(a, bf, acc[nt], 0, 0, 0);
            }
        }

        const float* bias = layer ? b2 : b1;
        if (layer == 0) {
            __syncthreads();
#pragma unroll
            for (int nt = 0; nt < 8; ++nt) {
                float bv = bias[nt * 16 + l15];
#pragma unroll
                for (int r = 0; r < 4; ++r) {
                    float v = fmaxf(acc[nt][r] + bv, 0.f);
                    hlds[(w * 16 + quad * 4 + r) * 136 + nt * 16 + l15] = f2bf(v);
                }
            }
        } else {
#pragma unroll
            for (int nt = 0; nt < 8; ++nt) {
                float bv = bias[nt * 16 + l15];
#pragma unroll
                for (int r = 0; r < 4; ++r) {
                    int node = node0 + w * 16 + quad * 4 + r;
                    if (node < N)
                        out[(size_t)node * DFEAT + nt * 16 + l15] = acc[nt][r] + bv;
                }
            }
        }
    }
}

// ===========================================================================
// Fallback (tiny ws): atomic scatter + fp32 vector MLP
// ===========================================================================
__global__ void detect_idx_kernel(const int* __restrict__ ei, int* __restrict__ flag) {
    if (threadIdx.x == 0 && blockIdx.x == 0) {
        int orsum = 0;
#pragma unroll
        for (int i = 0; i < 128; ++i) orsum |= ei[2 * i + 1];
        flag[0] = (orsum == 0) ? 1 : 0;
    }
}

__global__ __launch_bounds__(256) void scatter_kernel(
        const float* __restrict__ x, const void* __restrict__ eiv,
        const int* __restrict__ flag, float* __restrict__ agg, int E) {
    unsigned gid = blockIdx.x * 256u + threadIdx.x;
    unsigned e = gid >> 5;
    if (e >= (unsigned)E) return;
    int c = (gid & 31u) * 4;
    int is64 = flag[0];
    int src = load_idx(eiv, is64, (size_t)e);
    int dst = load_idx(eiv, is64, (size_t)E + e);
    float4 v = *(const float4*)&x[(size_t)src * DFEAT + c];
    float* p = &agg[(size_t)dst * DFEAT + c];
    unsafeAtomicAdd(p + 0, v.x);
    unsafeAtomicAdd(p + 1, v.y);
    unsafeAtomicAdd(p + 2, v.z);
    unsafeAtomicAdd(p + 3, v.w);
}

__global__ __launch_bounds__(256) void mlp_kernel(
        const float* __restrict__ xp,
        const float* __restrict__ W1, const float* __restrict__ b1,
        const float* __restrict__ W2, const float* __restrict__ b2,
        const float* __restrict__ epsp, float* __restrict__ out) {
    __shared__ float hs[32][DFEAT];
    __shared__ float Wc[64][DFEAT];

    const int tid = threadIdx.x;
    const int node0 = blockIdx.x * 32;
    const float epsv = 1.0f + epsp[0];

    for (int i = tid; i < 32 * (DFEAT / 4); i += 256) {
        int n = i >> 5;
        int c = (i & 31) * 4;
        size_t off = (size_t)(node0 + n) * DFEAT + c;
        float4 h = *(const float4*)&out[off];
        float4 xv = *(const float4*)&xp[off];
        h.x += epsv * xv.x; h.y += epsv * xv.y;
        h.z += epsv * xv.z; h.w += epsv * xv.w;
        *(float4*)&hs[n][c] = h;
    }

    const int og = (tid & 31) * 4;
    const int ng = (tid >> 5) * 4;

    for (int layer = 0; layer < 2; ++layer) {
        const float* W = layer ? W2 : W1;
        const float* b = layer ? b2 : b1;

        float acc[4][4];
#pragma unroll
        for (int j = 0; j < 4; ++j) {
            float bj = b[og + j];
#pragma unroll
            for (int i = 0; i < 4; ++i) acc[i][j] = bj;
        }

        for (int chunk = 0; chunk < 2; ++chunk) {
            __syncthreads();
            for (int i = tid; i < 64 * (DFEAT / 4); i += 256) {
                int r = i >> 5;
                int c = (i & 31) * 4;
                *(float4*)&Wc[r][c] =
                    *(const float4*)&W[(size_t)(chunk * 64 + r) * DFEAT + c];
            }
            __syncthreads();
            const int kb = chunk * 64;
            for (int k = 0; k < 64; k += 4) {
                float4 h4[4], w4[4];
#pragma unroll
                for (int i = 0; i < 4; ++i)
                    h4[i] = *(const float4*)&hs[ng + i][kb + k];
#pragma unroll
                for (int j = 0; j < 4; ++j)
                    w4[j] = *(const float4*)&Wc[k + j][og];
#pragma unroll
                for (int i = 0; i < 4; ++i) {
                    acc[i][0] += h4[i].x * w4[0].x + h4[i].y * w4[1].x
                               + h4[i].z * w4[2].x + h4[i].w * w4[3].x;
                    acc[i][1] += h4[i].x * w4[0].y + h4[i].y * w4[1].y
                               + h4[i].z * w4[2].y + h4[i].w * w4[3].y;
                    acc[i][2] += h4[i].x * w4[0].z + h4[i].y * w4[1].z
                               + h4[i].z * w4[2].z + h4[i].w * w4[3].z;
                    acc[i][3] += h4[i].x * w4[0].w + h4[i].y * w4[1].w
                               + h4[i].z * w4[2].w + h4[i].w * w4[3].w;
                }
            }
        }
        __syncthreads();

        if (layer == 0) {
#pragma unroll
            for (int i = 0; i < 4; ++i) {
                float4 r;
                r.x = fmaxf(acc[i][0], 0.0f);
                r.y = fmaxf(acc[i][1], 0.0f);
                r.z = fmaxf(acc[i][2], 0.0f);
                r.w = fmaxf(acc[i][3], 0.0f);
                *(float4*)&hs[ng + i][og] = r;
            }
        } else {
#pragma unroll
            for (int i = 0; i < 4; ++i) {
                float4 r;
                r.x = acc[i][0]; r.y = acc[i][1];
                r.z = acc[i][2]; r.w = acc[i][3];
                *(float4*)&out[(size_t)(node0 + ng + i) * DFEAT + og] = r;
            }
        }
    }
}

extern "C" void kernel_launch(void* const* d_in, const int* in_sizes, int n_in,
                              void* d_out, int out_size, void* d_ws, size_t ws_size,
                              hipStream_t stream) {
    const float* x   = (const float*)d_in[0];
    const void*  ei  = d_in[1];
    const float* W1  = (const float*)d_in[2];
    const float* b1  = (const float*)d_in[3];
    const float* W2  = (const float*)d_in[4];
    const float* b2  = (const float*)d_in[5];
    const float* eps = (const float*)d_in[6];
    float* out = (float*)d_out;

    const int N = in_sizes[0] / DFEAT;      // 100000
    const int E = in_sizes[1] / 2;          // 1600000
    const int M = NGRP * N;                 // 800000 segments
    const int total4 = N * (DFEAT / 4);     // 3.2M float4s in x

    // ---- layout: [w1bf][w2bf][xb][counts][ovcnt][ov][slab][hb?] ----
    char* p = (char*)d_ws;
    unsigned short* w1bf = (unsigned short*)p;  p += 128 * 128 * 2;
    unsigned short* w2bf = (unsigned short*)p;  p += 128 * 128 * 2;
    unsigned short* xb = (unsigned short*)p;    p += (size_t)N * DFEAT * 2;
    int* counts = (int*)p;                      p += (size_t)M * 4;
    int* ovcnt = (int*)p;                       p += 64;
    int2* ov = (int2*)p;                        p += (size_t)OVCAP * 8;
    int* slab = (int*)p;                        p += (size_t)M * SSLOT * 4;
    size_t need_slim = (size_t)(p - (char*)d_ws);
    unsigned short* hb = (unsigned short*)p;    p += (size_t)N * DFEAT * 2;
    size_t need_full = (size_t)(p - (char*)d_ws);

    if (ws_size >= need_slim) {
        bool full = (ws_size >= need_full);
        int nfill = FILL_BLOCKS;
        if ((size_t)E > (size_t)FILL_BLOCKS * 256 * EPT)
            nfill = (E + 256 * EPT - 1) / (256 * EPT);
        int xbBlocks = (total4 + 255) / 256;

        hipMemsetAsync(counts, 0, (size_t)M * 4 + 64, stream);  // counts+ovcnt
        prep_kernel<<<nfill + 128 + xbBlocks, 256, 0, stream>>>(
            W1, W2, w1bf, w2bf, x, xb, total4, ei,
            counts, ovcnt, ov, slab, E, N, nfill);
        agg_slab_kernel<<<(N + 7) / 8, 256, 0, stream>>>(
            xb, counts, slab, ovcnt, ov, eps,
            full ? hb : nullptr, out, N);
        mlp_mfma_kernel<<<(N + 63) / 64, 256, 0, stream>>>(
            full ? hb : nullptr, out, w1bf, w2bf, b1, b2, out, N);
        return;
    }

    // ---- fallback: atomic scatter + fp32 MLP ----
    int* flag3 = (int*)d_ws;
    detect_idx_kernel<<<1, 64, 0, stream>>>((const int*)ei, flag3);
    hipMemsetAsync(d_out, 0, (size_t)out_size * sizeof(float), stream);
    unsigned total = (unsigned)E * 32u;
    scatter_kernel<<<(total + 255u) / 256u, 256, 0, stream>>>(x, ei, flag3, out, E);
    mlp_kernel<<<N / 32, 256, 0, stream>>>(x, W1, b1, W2, b2, eps, out);
}

// Round 7
// 244.162 us; speedup vs baseline: 1.5135x; 1.2081x over previous
//
#include <hip/hip_runtime.h>

#define DFEAT 128
#define NA 512           // phase-A blocks (edge chunks)
#define CELLW 20         // words per (bucket, ablock) cell: {cnt, 19 entries}
#define CAPAB 19         // payload entries per cell (lambda~8, P(>19)~1e-4)
#define MAXBKT 512       // static LDS sizing; requires N <= 131072
#define CAPB 4608        // per-bucket sorted-list capacity (lambda 4096, +8 sigma)
#define OVCAP 32768      // overflow list capacity (~20 expected)

typedef __attribute__((ext_vector_type(8))) short short8v;   // 8 bf16
typedef __attribute__((ext_vector_type(4))) float f32x4;     // MFMA C/D
typedef __attribute__((ext_vector_type(4))) unsigned short ushort4v;

__device__ __forceinline__ unsigned short f2bf(float f) {
    union { float f; unsigned u; } cv; cv.f = f;
    unsigned u = cv.u + 0x7fffu + ((cv.u >> 16) & 1u);   // RNE
    return (unsigned short)(u >> 16);
}
__device__ __forceinline__ float bf2f(unsigned short h) {
    union { unsigned u; float f; } cv; cv.u = ((unsigned)h) << 16; return cv.f;
}
__device__ __forceinline__ int load_idx(const void* eiv, int is64, size_t i) {
    return is64 ? (int)((const long long*)eiv)[i] : ((const int*)eiv)[i];
}

// ---------------------------------------------------------------------------
// Fused prep v8: LDS-binned edge partition (blocks 0..NA-1) + W->bf16^T
// (next 128) + x->bf16 (rest). Replaces the global-atomic fill that rounds
// 0-6 proved pinned at ~95-115us (~16 random TCC ops/cycle, insensitive to
// layout/scope/payload). All contended RMWs now hit CU-local LDS; all global
// writes are streams. Cell = {cnt, 19 x ((dst&255)<<17 | src)}; bucket-major
// gbuf so phase B reads each bucket as one dense 40KB span.
// Only ovcnt needs pre-zeroing (64B memset).
// ---------------------------------------------------------------------------
__global__ __launch_bounds__(256) void prep_kernel(
        const float* __restrict__ W1, const float* __restrict__ W2,
        unsigned short* __restrict__ w1bf, unsigned short* __restrict__ w2bf,
        const float* __restrict__ x, unsigned short* __restrict__ xb, int total4,
        const void* __restrict__ eiv,
        unsigned* __restrict__ gbuf, int* __restrict__ ovcnt,
        int2* __restrict__ ov,
        int E, int N, int nbkt) {
    const int b = blockIdx.x;

    if (b < NA) {
        __shared__ unsigned lcnt[MAXBKT];
        __shared__ unsigned lbuf[MAXBKT * CELLW];

        const int* e32 = (const int*)eiv;
        int orsum = 0;
#pragma unroll
        for (int i = 0; i < 128; ++i) orsum |= e32[2 * i + 1];
        const int is64 = (orsum == 0);

        for (int w = threadIdx.x; w < nbkt; w += 256) lcnt[w] = 0;
        __syncthreads();

        const int chunk = (E + NA - 1) / NA;
        const int e0 = b * chunk;
        const int eEnd = min(e0 + chunk, E);
        for (int e = e0 + threadIdx.x; e < eEnd; e += 256) {
            int src = load_idx(eiv, is64, (size_t)e);
            int dst = load_idx(eiv, is64, (size_t)E + e);
            int bkt = dst >> 8;
            unsigned dl = (unsigned)(dst & 255);
            unsigned pos = atomicAdd(&lcnt[bkt], 1u);
            if (pos < CAPAB)
                lbuf[bkt * CELLW + 1 + pos] = (dl << 17) | (unsigned)src;
            else {
                int o = atomicAdd(ovcnt, 1);
                if (o < OVCAP) ov[o] = make_int2(dst, src);
            }
        }
        __syncthreads();
        for (int w = threadIdx.x; w < nbkt; w += 256)
            lbuf[w * CELLW] = min(lcnt[w], (unsigned)CAPAB);
        __syncthreads();
        const int tot = nbkt * CELLW;
        for (int w = threadIdx.x; w < tot; w += 256) {
            int k = w / CELLW, slot = w - k * CELLW;
            gbuf[((size_t)k * NA + b) * CELLW + slot] = lbuf[w];
        }
    } else if (b < NA + 128) {
        // ---- W -> bf16 transposed ----
        int wb = b - NA;
        const float* W = (wb < 64) ? W1 : W2;
        unsigned short* o = (wb < 64) ? w1bf : w2bf;
        int idx = (wb & 63) * 256 + threadIdx.x;   // idx = k*128+n
        int kk = idx >> 7, n = idx & 127;
        o[n * 128 + kk] = f2bf(W[idx]);
    } else {
        // ---- x -> bf16 ----
        int i = (b - NA - 128) * 256 + threadIdx.x;
        if (i < total4) {
            float4 v = *(const float4*)&x[(size_t)i * 4];
            ushort4v o;
            o.x = f2bf(v.x); o.y = f2bf(v.y); o.z = f2bf(v.z); o.w = f2bf(v.w);
            *(ushort4v*)&xb[(size_t)i * 4] = o;
        }
    }
}

// ---------------------------------------------------------------------------
// agg_sort v8: one 512-thread block per bucket (256 nodes). Thread t loads
// cell (bucket, ablock=t) as 5 x uint4 (dense 40KB span per block), LDS
// counting-sort by node slot (hist -> Hillis-Steele scan -> scatter), then
// 16 teams x 32 lanes run the proven 16-wide batched row gather with each
// node's neighbor srcs CONTIGUOUS in LDS (no compaction). Overflow (~20
// entries) replayed by ballot. h = (1+eps)*x[n] + sum x[s].
// ---------------------------------------------------------------------------
__global__ __launch_bounds__(512) void agg_sort_kernel(
        const unsigned short* __restrict__ xb,
        const unsigned* __restrict__ gbuf,
        const int* __restrict__ ovcnt, const int2* __restrict__ ov,
        const float* __restrict__ epsp,
        unsigned short* __restrict__ hb,      // bf16 h out (may be null)
        float* __restrict__ hf,               // fp32 h out (used if hb null)
        int N) {
    __shared__ int cnt_s[256];
    __shared__ int scanA[256];
    __shared__ int start_s[257];
    __shared__ int srcS[CAPB];

    const int t = threadIdx.x;
    const int b = blockIdx.x;
    const int node0 = b << 8;

    // ---- load my cell (ablock = t), fully static unpack ----
    const uint4* cp = (const uint4*)&gbuf[((size_t)b * NA + t) * CELLW];
    uint4 c0 = cp[0], c1 = cp[1], c2 = cp[2], c3 = cp[3], c4 = cp[4];
    unsigned eb[CELLW];
    eb[0]  = c0.x; eb[1]  = c0.y; eb[2]  = c0.z; eb[3]  = c0.w;
    eb[4]  = c1.x; eb[5]  = c1.y; eb[6]  = c1.z; eb[7]  = c1.w;
    eb[8]  = c2.x; eb[9]  = c2.y; eb[10] = c2.z; eb[11] = c2.w;
    eb[12] = c3.x; eb[13] = c3.y; eb[14] = c3.z; eb[15] = c3.w;
    eb[16] = c4.x; eb[17] = c4.y; eb[18] = c4.z; eb[19] = c4.w;
    const int myc = (int)eb[0];               // <= CAPAB

    if (t < 256) cnt_s[t] = 0;
    __syncthreads();
#pragma unroll
    for (int k = 1; k <= CAPAB; ++k)
        if (k <= myc) atomicAdd(&cnt_s[eb[k] >> 17], 1);
    __syncthreads();

    // ---- Hillis-Steele inclusive scan of cnt_s -> start_s (exclusive) ----
    if (t < 256) scanA[t] = cnt_s[t];
    __syncthreads();
    for (int off = 1; off < 256; off <<= 1) {
        int v = 0;
        if (t < 256) { v = scanA[t]; if (t >= off) v += scanA[t - off]; }
        __syncthreads();
        if (t < 256) scanA[t] = v;
        __syncthreads();
    }
    if (t < 256) start_s[t + 1] = scanA[t];
    if (t == 0) start_s[0] = 0;
    __syncthreads();
    if (t < 256) cnt_s[t] = start_s[t];       // cursor
    __syncthreads();

    // ---- scatter into sorted per-node lists ----
#pragma unroll
    for (int k = 1; k <= CAPAB; ++k)
        if (k <= myc) {
            int dl = (int)(eb[k] >> 17);
            int pos = atomicAdd(&cnt_s[dl], 1);
            if (pos < CAPB) srcS[pos] = (int)(eb[k] & 0x1FFFFu);
        }
    __syncthreads();

    // ---- gather: 16 teams x 32 lanes ----
    const int lane = t & 31;
    const int team = t >> 5;                  // 0..15
    const int base = t & 32;                  // ballot shift within 64-lane wave
    const int c = lane * 4;
    const float epsv = 1.0f + epsp[0];
    const int ovn = min(ovcnt[0], OVCAP);
    const int trips = (ovn + 31) >> 5;

    for (int jj = team; jj < 256; jj += 16) {
        int node = node0 + jj;
        if (node >= N) break;                 // ascending: later jj also >= N
        int s = start_s[jj];
        int cnt = start_s[jj + 1] - s;

        ushort4v own = *(const ushort4v*)&xb[(size_t)node * DFEAT + c];
        float ax = epsv * bf2f(own.x), ay = epsv * bf2f(own.y);
        float az = epsv * bf2f(own.z), aw = epsv * bf2f(own.w);

        for (int i = 0; i < cnt; i += 16) {
            int rem = cnt - i;
            int sj[16];
#pragma unroll
            for (int q = 0; q < 16; ++q)
                sj[q] = srcS[s + ((i + q < cnt) ? (i + q) : (cnt - 1))];
            ushort4v u[16];
#pragma unroll
            for (int q = 0; q < 16; ++q)
                u[q] = *(const ushort4v*)&xb[(size_t)sj[q] * DFEAT + c];
#pragma unroll
            for (int q = 0; q < 16; ++q) {
                if (rem > q) {
                    ax += bf2f(u[q].x); ay += bf2f(u[q].y);
                    az += bf2f(u[q].z); aw += bf2f(u[q].w);
                }
            }
        }

        // overflow replay (tiny list, L2-resident)
        for (int tt = 0; tt < trips; ++tt) {
            int j = tt * 32 + lane;
            int2 eo = (j < ovn) ? ov[j] : make_int2(-1, 0);
            unsigned long long bm = __ballot(eo.x == node);
            unsigned m = (unsigned)(bm >> base);
            while (m) {
                int l = __ffs(m) - 1; m &= m - 1;
                int sv = __shfl(eo.y, base + l, 64);
                ushort4v u = *(const ushort4v*)&xb[(size_t)sv * DFEAT + c];
                ax += bf2f(u.x); ay += bf2f(u.y);
                az += bf2f(u.z); aw += bf2f(u.w);
            }
        }

        if (hb) {
            ushort4v hv;
            hv.x = f2bf(ax); hv.y = f2bf(ay); hv.z = f2bf(az); hv.w = f2bf(aw);
            *(ushort4v*)&hb[(size_t)node * DFEAT + c] = hv;
        } else {
            *(float4*)&hf[(size_t)node * DFEAT + c] = make_float4(ax, ay, az, aw);
        }
    }
}

// ---------------------------------------------------------------------------
// MFMA MLP (R4-proven): out = relu(h@W1+b1)@W2+b2, bf16 in / fp32 accum.
// ---------------------------------------------------------------------------
__global__ __launch_bounds__(256) void mlp_mfma_kernel(
        const unsigned short* __restrict__ hb,
        const float* __restrict__ hsrc,
        const unsigned short* __restrict__ w1bf,
        const unsigned short* __restrict__ w2bf,
        const float* __restrict__ b1, const float* __restrict__ b2,
        float* __restrict__ out, int N) {
    __shared__ unsigned short hlds[64 * 136];
    __shared__ unsigned short wlds[128 * 136];

    const int tid  = threadIdx.x;
    const int node0 = blockIdx.x * 64;
    const int lane = tid & 63;
    const int w    = tid >> 6;
    const int l15  = lane & 15;
    const int quad = lane >> 4;

    if (hb) {
        for (int i = tid; i < 64 * 16; i += 256) {
            int m = i >> 4, k0 = (i & 15) * 8;
            int node = node0 + m;
            short8v v = {0, 0, 0, 0, 0, 0, 0, 0};
            if (node < N) v = *(const short8v*)&hb[(size_t)node * DFEAT + k0];
            *(short8v*)&hlds[m * 136 + k0] = v;
        }
    } else {
        for (int i = tid; i < 64 * 32; i += 256) {
            int m = i >> 5, c = (i & 31) * 4;
            int node = node0 + m;
            float4 v = make_float4(0.f, 0.f, 0.f, 0.f);
            if (node < N) v = *(const float4*)&hsrc[(size_t)node * DFEAT + c];
            ushort4v o;
            o.x = f2bf(v.x); o.y = f2bf(v.y); o.z = f2bf(v.z); o.w = f2bf(v.w);
            *(ushort4v*)&hlds[m * 136 + c] = o;
        }
    }
    for (int i = tid; i < 128 * 16; i += 256) {
        int n = i >> 4, k0 = (i & 15) * 8;
        *(short8v*)&wlds[n * 136 + k0] = *(const short8v*)&w1bf[n * 128 + k0];
    }
    __syncthreads();

    const unsigned short* ha = &hlds[(w * 16 + l15) * 136 + quad * 8];

    for (int layer = 0; layer < 2; ++layer) {
        if (layer == 1) {
            __syncthreads();
            for (int i = tid; i < 128 * 16; i += 256) {
                int n = i >> 4, k0 = (i & 15) * 8;
                *(short8v*)&wlds[n * 136 + k0] = *(const short8v*)&w2bf[n * 128 + k0];
            }
            __syncthreads();
        }

        f32x4 acc[8];
#pragma unroll
        for (int nt = 0; nt < 8; ++nt) acc[nt] = (f32x4){0.f, 0.f, 0.f, 0.f};

#pragma unroll
        for (int s = 0; s < 4; ++s) {
            short8v a = *(const short8v*)&ha[s * 32];
#pragma unroll
            for (int nt = 0; nt < 8; ++nt) {
                short8v bf = *(const short8v*)&wlds[(nt * 16 + l15) * 136 + quad * 8 + s * 32];
                acc[nt] = __builtin_amdgcn_mfma_f32_16x16x32_bf16(a, bf, acc[nt], 0, 0, 0);
            }
        }

        const float* bias = layer ? b2 : b1;
        if (layer == 0) {
            __syncthreads();
#pragma unroll
            for (int nt = 0; nt < 8; ++nt) {
                float bv = bias[nt * 16 + l15];
#pragma unroll
                for (int r = 0; r < 4; ++r) {
                    float v = fmaxf(acc[nt][r] + bv, 0.f);
                    hlds[(w * 16 + quad * 4 + r) * 136 + nt * 16 + l15] = f2bf(v);
                }
            }
        } else {
#pragma unroll
            for (int nt = 0; nt < 8; ++nt) {
                float bv = bias[nt * 16 + l15];
#pragma unroll
                for (int r = 0; r < 4; ++r) {
                    int node = node0 + w * 16 + quad * 4 + r;
                    if (node < N)
                        out[(size_t)node * DFEAT + nt * 16 + l15] = acc[nt][r] + bv;
                }
            }
        }
    }
}

// ===========================================================================
// Fallback (tiny ws): atomic scatter + fp32 vector MLP
// ===========================================================================
__global__ void detect_idx_kernel(const int* __restrict__ ei, int* __restrict__ flag) {
    if (threadIdx.x == 0 && blockIdx.x == 0) {
        int orsum = 0;
#pragma unroll
        for (int i = 0; i < 128; ++i) orsum |= ei[2 * i + 1];
        flag[0] = (orsum == 0) ? 1 : 0;
    }
}

__global__ __launch_bounds__(256) void scatter_kernel(
        const float* __restrict__ x, const void* __restrict__ eiv,
        const int* __restrict__ flag, float* __restrict__ agg, int E) {
    unsigned gid = blockIdx.x * 256u + threadIdx.x;
    unsigned e = gid >> 5;
    if (e >= (unsigned)E) return;
    int c = (gid & 31u) * 4;
    int is64 = flag[0];
    int src = load_idx(eiv, is64, (size_t)e);
    int dst = load_idx(eiv, is64, (size_t)E + e);
    float4 v = *(const float4*)&x[(size_t)src * DFEAT + c];
    float* p = &agg[(size_t)dst * DFEAT + c];
    unsafeAtomicAdd(p + 0, v.x);
    unsafeAtomicAdd(p + 1, v.y);
    unsafeAtomicAdd(p + 2, v.z);
    unsafeAtomicAdd(p + 3, v.w);
}

__global__ __launch_bounds__(256) void mlp_kernel(
        const float* __restrict__ xp,
        const float* __restrict__ W1, const float* __restrict__ b1,
        const float* __restrict__ W2, const float* __restrict__ b2,
        const float* __restrict__ epsp, float* __restrict__ out) {
    __shared__ float hs[32][DFEAT];
    __shared__ float Wc[64][DFEAT];

    const int tid = threadIdx.x;
    const int node0 = blockIdx.x * 32;
    const float epsv = 1.0f + epsp[0];

    for (int i = tid; i < 32 * (DFEAT / 4); i += 256) {
        int n = i >> 5;
        int c = (i & 31) * 4;
        size_t off = (size_t)(node0 + n) * DFEAT + c;
        float4 h = *(const float4*)&out[off];
        float4 xv = *(const float4*)&xp[off];
        h.x += epsv * xv.x; h.y += epsv * xv.y;
        h.z += epsv * xv.z; h.w += epsv * xv.w;
        *(float4*)&hs[n][c] = h;
    }

    const int og = (tid & 31) * 4;
    const int ng = (tid >> 5) * 4;

    for (int layer = 0; layer < 2; ++layer) {
        const float* W = layer ? W2 : W1;
        const float* b = layer ? b2 : b1;

        float acc[4][4];
#pragma unroll
        for (int j = 0; j < 4; ++j) {
            float bj = b[og + j];
#pragma unroll
            for (int i = 0; i < 4; ++i) acc[i][j] = bj;
        }

        for (int chunk = 0; chunk < 2; ++chunk) {
            __syncthreads();
            for (int i = tid; i < 64 * (DFEAT / 4); i += 256) {
                int r = i >> 5;
                int c = (i & 31) * 4;
                *(float4*)&Wc[r][c] =
                    *(const float4*)&W[(size_t)(chunk * 64 + r) * DFEAT + c];
            }
            __syncthreads();
            const int kb = chunk * 64;
            for (int k = 0; k < 64; k += 4) {
                float4 h4[4], w4[4];
#pragma unroll
                for (int i = 0; i < 4; ++i)
                    h4[i] = *(const float4*)&hs[ng + i][kb + k];
#pragma unroll
                for (int j = 0; j < 4; ++j)
                    w4[j] = *(const float4*)&Wc[k + j][og];
#pragma unroll
                for (int i = 0; i < 4; ++i) {
                    acc[i][0] += h4[i].x * w4[0].x + h4[i].y * w4[1].x
                               + h4[i].z * w4[2].x + h4[i].w * w4[3].x;
                    acc[i][1] += h4[i].x * w4[0].y + h4[i].y * w4[1].y
                               + h4[i].z * w4[2].y + h4[i].w * w4[3].y;
                    acc[i][2] += h4[i].x * w4[0].z + h4[i].y * w4[1].z
                               + h4[i].z * w4[2].z + h4[i].w * w4[3].z;
                    acc[i][3] += h4[i].x * w4[0].w + h4[i].y * w4[1].w
                               + h4[i].z * w4[2].w + h4[i].w * w4[3].w;
                }
            }
        }
        __syncthreads();

        if (layer == 0) {
#pragma unroll
            for (int i = 0; i < 4; ++i) {
                float4 r;
                r.x = fmaxf(acc[i][0], 0.0f);
                r.y = fmaxf(acc[i][1], 0.0f);
                r.z = fmaxf(acc[i][2], 0.0f);
                r.w = fmaxf(acc[i][3], 0.0f);
                *(float4*)&hs[ng + i][og] = r;
            }
        } else {
#pragma unroll
            for (int i = 0; i < 4; ++i) {
                float4 r;
                r.x = acc[i][0]; r.y = acc[i][1];
                r.z = acc[i][2]; r.w = acc[i][3];
                *(float4*)&out[(size_t)(node0 + ng + i) * DFEAT + og] = r;
            }
        }
    }
}

extern "C" void kernel_launch(void* const* d_in, const int* in_sizes, int n_in,
                              void* d_out, int out_size, void* d_ws, size_t ws_size,
                              hipStream_t stream) {
    const float* x   = (const float*)d_in[0];
    const void*  ei  = d_in[1];
    const float* W1  = (const float*)d_in[2];
    const float* b1  = (const float*)d_in[3];
    const float* W2  = (const float*)d_in[4];
    const float* b2  = (const float*)d_in[5];
    const float* eps = (const float*)d_in[6];
    float* out = (float*)d_out;

    const int N = in_sizes[0] / DFEAT;      // 100000
    const int E = in_sizes[1] / 2;          // 1600000
    const int total4 = N * (DFEAT / 4);     // 3.2M float4s in x
    const int nbkt = (N + 255) >> 8;        // 391 node-range buckets

    // ---- layout: [w1bf][w2bf][xb][ov][ovcnt][gbuf][hb?] ----
    char* p = (char*)d_ws;
    unsigned short* w1bf = (unsigned short*)p;  p += 128 * 128 * 2;
    unsigned short* w2bf = (unsigned short*)p;  p += 128 * 128 * 2;
    unsigned short* xb = (unsigned short*)p;    p += (size_t)N * DFEAT * 2;
    int2* ov = (int2*)p;                        p += (size_t)OVCAP * 8;  // 256KB
    int* ovcnt = (int*)p;                       p += 64;
    unsigned* gbuf = (unsigned*)p;              p += (size_t)nbkt * NA * CELLW * 4; // 16MB
    size_t need_slim = (size_t)(p - (char*)d_ws);
    unsigned short* hb = (unsigned short*)p;    p += (size_t)N * DFEAT * 2;
    size_t need_full = (size_t)(p - (char*)d_ws);

    if (ws_size >= need_slim && nbkt <= MAXBKT) {
        bool full = (ws_size >= need_full);
        int xbBlocks = (total4 + 255) / 256;

        hipMemsetAsync(ovcnt, 0, 64, stream);
        prep_kernel<<<NA + 128 + xbBlocks, 256, 0, stream>>>(
            W1, W2, w1bf, w2bf, x, xb, total4, ei,
            gbuf, ovcnt, ov, E, N, nbkt);
        agg_sort_kernel<<<nbkt, 512, 0, stream>>>(
            xb, gbuf, ovcnt, ov, eps,
            full ? hb : nullptr, out, N);
        mlp_mfma_kernel<<<(N + 63) / 64, 256, 0, stream>>>(
            full ? hb : nullptr, out, w1bf, w2bf, b1, b2, out, N);
        return;
    }

    // ---- fallback: atomic scatter + fp32 MLP ----
    int* flag3 = (int*)d_ws;
    detect_idx_kernel<<<1, 64, 0, stream>>>((const int*)ei, flag3);
    hipMemsetAsync(d_out, 0, (size_t)out_size * sizeof(float), stream);
    unsigned total = (unsigned)E * 32u;
    scatter_kernel<<<(total + 255u) / 256u, 256, 0, stream>>>(x, ei, flag3, out, E);
    mlp_kernel<<<N / 32, 256, 0, stream>>>(x, W1, b1, W2, b2, eps, out);
}